// Round 1
// baseline (340.890 us; speedup 1.0000x reference)
//
#include <hip/hip_runtime.h>

#define HW    1024
#define C_CH  512

// ws layout (floats): S[8][4096] @0 (written by reduce, no zeroing needed),
//                     chansum[512] @32768 (zeroed), v0f[512] @33280,
//                     w2[512] @33792, b2[512] @34304
// d_out doubles as scratch for cov partial tiles: Spart[1024][4096] (16.8 MB),
// consumed by reduce_kernel BEFORE apply_kernel overwrites d_out.

// ---------------------------------------------------------------------------
// K1: per-(g,n,ks) Gram partial of a 64ch x 512hw slab. 1024 blocks x 256 thr.
// Gram is symmetric: only the 136 upper-triangle 4x4 tiles are computed
// (threads 0..135; wave 3 idle in compute), mirrored on write. Cuts compute
// LDS reads + FMAs ~47% vs full 256-tile version.
// LDS 16 KB, XOR-swizzled k-major tile: logical As[kk][row] lives at word
//   kk*64 + 4*((row>>2)^(kk>>2)) + (row&3)
// -> staging scalar writes hit 64 distinct words (2-way banks, free);
// -> compute float4 reads stay 16B-aligned (per-kk XOR permutes 16B blocks).
// ---------------------------------------------------------------------------
__global__ __launch_bounds__(256, 4) void cov_kernel(const float* __restrict__ x,
                                                     float* __restrict__ Spart,
                                                     float* __restrict__ chansum) {
  const int ks = blockIdx.x & 1;
  const int n  = (blockIdx.x >> 1) & 63;
  const int g  = blockIdx.x >> 7;
  __shared__ __align__(16) float As[4096];
  const int t = threadIdx.x;

  // map t -> upper-triangle tile (ti,tj), ti<=tj; row ti holds 16-ti tiles
  int ti = 0, rem = t;
  while (ti < 16 && rem >= 16 - ti) { rem -= 16 - ti; ++ti; }
  const bool act = (t < 136);
  const int tj = act ? ti + rem : 0;
  if (!act) ti = 0;

  float acc[4][4];
#pragma unroll
  for (int r = 0; r < 4; r++)
#pragma unroll
    for (int s = 0; s < 4; s++) acc[r][s] = 0.f;
  float rsum = 0.f;

  const float* base = x + ((size_t)(n * C_CH + g * 64)) * HW;
  const int rlo = t >> 4;   // staging row low bits
  const int cc  = t & 15;   // staging col4 (= kk>>2)

  for (int chunk = 0; chunk < 8; chunk++) {
    const int k0 = ks * 512 + chunk * 64;
#pragma unroll
    for (int s = 0; s < 4; s++) {
      const int row = 16 * s + rlo;
      const float4 v = *(const float4*)(base + (size_t)row * HW + k0 + 4 * cc);
      const int w0 = 4 * ((row >> 2) ^ cc) + (row & 3);
      As[(4 * cc + 0) * 64 + w0] = v.x;
      As[(4 * cc + 1) * 64 + w0] = v.y;
      As[(4 * cc + 2) * 64 + w0] = v.z;
      As[(4 * cc + 3) * 64 + w0] = v.w;
    }
    __syncthreads();
    if (act) {
#pragma unroll 16
      for (int kk = 0; kk < 64; kk++) {
        const int kq = kk >> 2;
        const float4 a = *(const float4*)&As[kk * 64 + 4 * (ti ^ kq)];
        const float4 b = *(const float4*)&As[kk * 64 + 4 * (tj ^ kq)];
        acc[0][0] += a.x * b.x; acc[0][1] += a.x * b.y; acc[0][2] += a.x * b.z; acc[0][3] += a.x * b.w;
        acc[1][0] += a.y * b.x; acc[1][1] += a.y * b.y; acc[1][2] += a.y * b.z; acc[1][3] += a.y * b.w;
        acc[2][0] += a.z * b.x; acc[2][1] += a.z * b.y; acc[2][2] += a.z * b.z; acc[2][3] += a.z * b.w;
        acc[3][0] += a.w * b.x; acc[3][1] += a.w * b.y; acc[3][2] += a.w * b.z; acc[3][3] += a.w * b.w;
      }
    }
    if (t < 64) {  // per-channel sum of this chunk (column t of the tile)
      float s2 = 0.f;
#pragma unroll 16
      for (int kk = 0; kk < 64; kk++)
        s2 += As[kk * 64 + 4 * ((t >> 2) ^ (kk >> 2)) + (t & 3)];
      rsum += s2;
    }
    __syncthreads();
  }

  // non-atomic partial tile -> d_out scratch; mirror lower triangle
  float* P = Spart + ((size_t)(g * 128 + n * 2 + ks)) * 4096;
  if (act) {
#pragma unroll
    for (int r = 0; r < 4; r++) {
      float4 w4;
      w4.x = acc[r][0]; w4.y = acc[r][1]; w4.z = acc[r][2]; w4.w = acc[r][3];
      *(float4*)&P[(4 * ti + r) * 64 + 4 * tj] = w4;
    }
    if (ti != tj) {
#pragma unroll
      for (int s = 0; s < 4; s++) {
        float4 w4;
        w4.x = acc[0][s]; w4.y = acc[1][s]; w4.z = acc[2][s]; w4.w = acc[3][s];
        *(float4*)&P[(4 * tj + s) * 64 + 4 * ti] = w4;
      }
    }
  }
  if (t < 64) atomicAdd(&chansum[g * 64 + t], rsum);
}

// ---------------------------------------------------------------------------
// K2: fold 128 partial tiles per group into S. 128 blocks x 256 thr.
// Single owner per entry -> plain store, no atomics, S needs no pre-zeroing.
// ---------------------------------------------------------------------------
__global__ __launch_bounds__(256) void reduce_kernel(const float* __restrict__ Spart,
                                                     float* __restrict__ S) {
  const int idx = blockIdx.x * 256 + threadIdx.x;  // 0..32767
  const int g   = idx >> 12;
  const int e   = idx & 4095;
  const float* P = Spart + ((size_t)(g * 128)) * 4096 + e;
  float s = 0.f;
#pragma unroll 16
  for (int p = 0; p < 128; p++) s += P[(size_t)p * 4096];
  S[idx] = s;
}

// ---------------------------------------------------------------------------
// K3: per-group top eigenpair of cov = S/M - mu muT + eps I.
// 12 in-place trace-normalized squarings of (C - sigma I) in fp32 LDS.
// B and B^2 are symmetric: compute upper-triangle 4x4 tiles only (136 threads),
// mirror on write -> ~47% less LDS traffic in the dominant squaring loop.
// fp64 power polish + Rayleigh. 8 blocks x 256 threads. LDS ~52 KB.
// ---------------------------------------------------------------------------
__global__ __launch_bounds__(256) void eigen_kernel(
    const float* __restrict__ S, const float* __restrict__ chansum,
    const float* __restrict__ weight, const float* __restrict__ bias,
    float* __restrict__ v0f, float* __restrict__ w2, float* __restrict__ b2) {
  const int g = blockIdx.x;
  __shared__ __align__(16) float Bf[64 * 68];  // 17408 B, stride 68
  __shared__ double Cd[64][65];                // 33280 B
  __shared__ double vv[64], uu[64];
  __shared__ double dred;
  __shared__ float f32red;
  __shared__ int ired;
  const int t = threadIdx.x;
  const double Minv = 1.0 / 65536.0;

  // upper-triangle tile map
  int ti = 0, rem = t;
  while (ti < 16 && rem >= 16 - ti) { rem -= 16 - ti; ++ti; }
  const bool act = (t < 136);
  const int tj = act ? ti + rem : 0;
  if (!act) ti = 0;

  for (int idx = t; idx < 4096; idx += 256) {
    const int i = idx >> 6, j = idx & 63;
    const double mui = (double)chansum[g * 64 + i] * Minv;
    const double muj = (double)chansum[g * 64 + j] * Minv;
    Cd[i][j] = (double)S[g * 4096 + idx] * Minv - mui * muj + (i == j ? 1e-4 : 0.0);
  }
  __syncthreads();
  if (t < 64) {  // PSD-safe shift: sigma = 0.49 * min(diag) <= 0.49*lam_min... < lam1/2
    double d = Cd[t][t];
#pragma unroll
    for (int off = 32; off; off >>= 1) d = fmin(d, __shfl_down(d, off));
    if (t == 0) f32red = (float)(0.49 * fmax(d, 0.0));
  }
  __syncthreads();
  const float sg = f32red;
  for (int idx = t; idx < 4096; idx += 256) {
    const int i = idx >> 6, j = idx & 63;
    Bf[i * 68 + j] = (float)Cd[i][j] - (i == j ? sg : 0.f);
  }
  __syncthreads();

  for (int it = 0; it < 12; it++) {
    if (t < 64) {
      float tr = Bf[t * 68 + t];
#pragma unroll
      for (int off = 32; off; off >>= 1) tr += __shfl_down(tr, off);
      if (t == 0) f32red = 1.f / tr;
    }
    __syncthreads();
    const float sc = f32red, scl = sc * sc;
    float acc[4][4];
#pragma unroll
    for (int r = 0; r < 4; r++)
#pragma unroll
      for (int s = 0; s < 4; s++) acc[r][s] = 0.f;
    if (act) {
#pragma unroll 16
      for (int kk = 0; kk < 64; kk++) {  // B symmetric: rows == cols
        const float4 a = *(const float4*)&Bf[kk * 68 + 4 * ti];
        const float4 b = *(const float4*)&Bf[kk * 68 + 4 * tj];
        acc[0][0] += a.x * b.x; acc[0][1] += a.x * b.y; acc[0][2] += a.x * b.z; acc[0][3] += a.x * b.w;
        acc[1][0] += a.y * b.x; acc[1][1] += a.y * b.y; acc[1][2] += a.y * b.z; acc[1][3] += a.y * b.w;
        acc[2][0] += a.z * b.x; acc[2][1] += a.z * b.y; acc[2][2] += a.z * b.z; acc[2][3] += a.z * b.w;
        acc[3][0] += a.w * b.x; acc[3][1] += a.w * b.y; acc[3][2] += a.w * b.z; acc[3][3] += a.w * b.w;
      }
    }
    __syncthreads();
    if (act) {
#pragma unroll
      for (int r = 0; r < 4; r++) {
        float4 w4;
        w4.x = acc[r][0] * scl; w4.y = acc[r][1] * scl;
        w4.z = acc[r][2] * scl; w4.w = acc[r][3] * scl;
        *(float4*)&Bf[(4 * ti + r) * 68 + 4 * tj] = w4;
      }
      if (ti != tj) {
#pragma unroll
        for (int s = 0; s < 4; s++) {
          float4 w4;
          w4.x = acc[0][s] * scl; w4.y = acc[1][s] * scl;
          w4.z = acc[2][s] * scl; w4.w = acc[3][s] * scl;
          *(float4*)&Bf[(4 * tj + s) * 68 + 4 * ti] = w4;
        }
      }
    }
    __syncthreads();
  }

  // dominant eigvec ~ column jstar of B^(2^12), jstar = argmax diag
  if (t < 64) {
    float d = Bf[t * 68 + t];
    int bj = t;
#pragma unroll
    for (int off = 32; off; off >>= 1) {
      const float od = __shfl_down(d, off);
      const int   oj = __shfl_down(bj, off);
      if (od > d) { d = od; bj = oj; }
    }
    if (t == 0) ired = bj;
  }
  __syncthreads();
  const int jstar = ired;
  if (t < 64) vv[t] = (double)Bf[t * 68 + jstar];
  __syncthreads();

  for (int pi = 0; pi < 3; pi++) {  // fp64 power polish
    if (t < 64) {
      double s = 0.0;
      for (int k = 0; k < 64; k++) s += Cd[t][k] * vv[k];
      uu[t] = s;
    }
    __syncthreads();
    if (t < 64) {
      double q = uu[t] * uu[t];
#pragma unroll
      for (int off = 32; off; off >>= 1) q += __shfl_down(q, off);
      if (t == 0) dred = 1.0 / sqrt(q);
    }
    __syncthreads();
    if (t < 64) vv[t] = uu[t] * dred;
    __syncthreads();
  }
  if (t < 64) {  // Rayleigh quotient
    double s = 0.0;
    for (int k = 0; k < 64; k++) s += Cd[t][k] * vv[k];
    uu[t] = s;
  }
  __syncthreads();
  if (t < 64) {
    double q = vv[t] * uu[t];
#pragma unroll
    for (int off = 32; off; off >>= 1) q += __shfl_down(q, off);
    if (t == 0) dred = 1.0 / sqrt(q);  // rsqrt(lam1)
  }
  __syncthreads();
  const double rsl = dred;
  double w2v = 0.0;
  if (t < 64) {
    const int c = g * 64 + t;
    v0f[c] = (float)vv[t];
    w2v = (double)weight[c] * rsl * vv[t];
    w2[c] = (float)w2v;
  }
  __syncthreads();
  if (t < 64) {  // d0 = v0 . mu, fold into bias
    double q = vv[t] * ((double)chansum[g * 64 + t] * Minv);
#pragma unroll
    for (int off = 32; off; off >>= 1) q += __shfl_down(q, off);
    if (t == 0) dred = q;
  }
  __syncthreads();
  if (t < 64) {
    const int c = g * 64 + t;
    b2[c] = (float)((double)bias[c] - w2v * dred);
  }
}

// ---------------------------------------------------------------------------
// K4: out[c][col] = w2[c] * (v0 . x[:,col]) + b2[c].  512 blocks x 256 thr,
// four columns/thread via float4: 16 B/lane = 1 KiB per wave instruction.
// HBM-bound (134 MB read + 134 MB write).
// ---------------------------------------------------------------------------
__global__ __launch_bounds__(256) void apply_kernel(
    const float* __restrict__ x, const float* __restrict__ v0f,
    const float* __restrict__ w2, const float* __restrict__ b2,
    float* __restrict__ out) {
  const int n = blockIdx.x & 63;
  const int g = blockIdx.x >> 6;
  __shared__ float vs[64], wsh[64], bsh[64];
  const int t = threadIdx.x;
  if (t < 64) {
    vs[t]  = v0f[g * 64 + t];
    wsh[t] = w2[g * 64 + t];
    bsh[t] = b2[g * 64 + t];
  }
  __syncthreads();
  const size_t boff = ((size_t)(n * C_CH + g * 64)) * HW + 4 * t;
  const float4* bx = (const float4*)(x + boff);
  float4 p = make_float4(0.f, 0.f, 0.f, 0.f);
#pragma unroll 8
  for (int l = 0; l < 64; l++) {
    const float4 v = bx[(size_t)l * (HW / 4)];
    p.x += vs[l] * v.x; p.y += vs[l] * v.y;
    p.z += vs[l] * v.z; p.w += vs[l] * v.w;
  }
  float4* bo = (float4*)(out + boff);
#pragma unroll 8
  for (int l = 0; l < 64; l++) {
    float4 o;
    o.x = wsh[l] * p.x + bsh[l]; o.y = wsh[l] * p.y + bsh[l];
    o.z = wsh[l] * p.z + bsh[l]; o.w = wsh[l] * p.w + bsh[l];
    bo[(size_t)l * (HW / 4)] = o;
  }
}

extern "C" void kernel_launch(void* const* d_in, const int* in_sizes, int n_in,
                              void* d_out, int out_size, void* d_ws, size_t ws_size,
                              hipStream_t stream) {
  const float* x      = (const float*)d_in[0];
  const float* weight = (const float*)d_in[1];
  const float* bias   = (const float*)d_in[2];
  float* out = (float*)d_out;
  float* ws  = (float*)d_ws;

  float* S       = ws;            // 32768 (fully written by reduce_kernel)
  float* chansum = ws + 32768;    // 512 (atomically accumulated -> zero it)
  float* v0f     = ws + 33280;    // 512
  float* w2      = ws + 33792;    // 512
  float* b2      = ws + 34304;    // 512
  float* Spart   = out;           // d_out as scratch: 1024*4096 floats (16.8 MB)

  hipMemsetAsync((char*)d_ws + 32768 * sizeof(float), 0, 512 * sizeof(float), stream);

  cov_kernel<<<dim3(1024), dim3(256), 0, stream>>>(x, Spart, chansum);
  reduce_kernel<<<dim3(128), dim3(256), 0, stream>>>(Spart, S);
  eigen_kernel<<<dim3(8), dim3(256), 0, stream>>>(S, chansum, weight, bias,
                                                  v0f, w2, b2);
  apply_kernel<<<dim3(512), dim3(256), 0, stream>>>(x, v0f, w2, b2, out);
}